// Round 5
// baseline (31736.844 us; speedup 1.0000x reference)
//
#include <hip/hip_runtime.h>

#define H 256
#define B 128
#define TE 240
#define TF 360
#define NK 241
#define NKH 121
#define BH (B*H)
#define KPSTR 130   // uints per LDS key row (128 + 2 pad -> 2-way-free banks)

// ---- LDS offsets (4-byte words) ----
#define OFF_KP    0
#define OFF_KEYS  (NKH*KPSTR)               // 15730
#define OFF_DW    (2*NKH*KPSTR)             // 31460 : 4x1024 f32 dec weights
#define OFF_SPART (OFF_DW + 4096)           // 2048 f32
#define OFF_SH2   (OFF_SPART + 2048)        // 256
#define OFF_SQ    (OFF_SH2 + 256)           // 256
#define OFF_SEXP  (OFF_SQ + 256)            // 256
#define OFF_SAV   (OFF_SEXP + 256)          // 256
#define OFF_SOW   (OFF_SAV + 256)           // 512
#define OFF_SRED  (OFF_SOW + 512)           // 8
#define OFF_SE    (OFF_SRED + 8)            // 64
#define SMEM_WORDS (OFF_SE + 64)
#define SMEM_BYTES (SMEM_WORDS*4)           // 156,848 B < 160 KiB

__device__ __forceinline__ float sigm(float x){ return 1.f/(1.f+__expf(-x)); }
__device__ __forceinline__ float ftanh(float x){ float e=__expf(2.f*x); return 1.f-2.f/(e+1.f); }
__device__ __forceinline__ float dot4(float4 a, float4 b){ return a.x*b.x+a.y*b.y+a.z*b.z+a.w*b.w; }
__device__ __forceinline__ float blo(unsigned u){ return __uint_as_float(u<<16); }
__device__ __forceinline__ float bhi(unsigned u){ return __uint_as_float(u & 0xffff0000u); }
__device__ __forceinline__ unsigned packbf(float a, float b){
    unsigned ua = __float_as_uint(a), ub = __float_as_uint(b);
    ua += 0x7fffu + ((ua>>16)&1u); ub += 0x7fffu + ((ub>>16)&1u);
    return (ua>>16) | (ub & 0xffff0000u);
}

// fenced grid barrier: release(wbL2) -> tree counters (relaxed) -> acquire(invL2)
__device__ __forceinline__ void gbar(unsigned* bar, unsigned step){
    __syncthreads();
    if (threadIdx.x == 0){
        __builtin_amdgcn_fence(__ATOMIC_RELEASE, "agent");
        unsigned g = (unsigned)blockIdx.x & 7u;
        unsigned o = __hip_atomic_fetch_add(&bar[g*32], 1u, __ATOMIC_RELAXED, __HIP_MEMORY_SCOPE_AGENT);
        if ((o & 31u) == 31u){
            unsigned rr = __hip_atomic_fetch_add(&bar[256+32], 1u, __ATOMIC_RELAXED, __HIP_MEMORY_SCOPE_AGENT);
            if ((rr & 7u) == 7u)
                __hip_atomic_fetch_add(&bar[256+64], 1u, __ATOMIC_RELAXED, __HIP_MEMORY_SCOPE_AGENT);
        }
        while (__hip_atomic_load(&bar[256+64], __ATOMIC_RELAXED, __HIP_MEMORY_SCOPE_AGENT) < step)
            __builtin_amdgcn_s_sleep(2);
        __builtin_amdgcn_fence(__ATOMIC_ACQUIRE, "agent");
    }
    __syncthreads();
}

// ---------------- CNN (one-shot) ----------------
template<int IC, int OC, int IN_HW, int OUT_HW>
__global__ void conv_relu(const float* __restrict__ in, const float* __restrict__ w,
                          const float* __restrict__ bias, float* __restrict__ out)
{
    int idx = blockIdx.x * blockDim.x + threadIdx.x;
    constexpr int total = B * OC * OUT_HW * OUT_HW;
    if (idx >= total) return;
    int x  = idx % OUT_HW;
    int y  = (idx / OUT_HW) % OUT_HW;
    int oc = (idx / (OUT_HW * OUT_HW)) % OC;
    int b  = idx / (OUT_HW * OUT_HW * OC);
    float acc = bias[oc];
    const float* wp = w + (size_t)oc * IC * 9;
    const float* ip = in + (size_t)b * IC * IN_HW * IN_HW;
    for (int ic = 0; ic < IC; ++ic) {
        const float* ipc = ip + (size_t)ic * IN_HW * IN_HW;
        const float* wpc = wp + ic * 9;
        #pragma unroll
        for (int ky = 0; ky < 3; ++ky) {
            int iy = 2 * y - 1 + ky;
            if ((unsigned)iy >= (unsigned)IN_HW) continue;
            #pragma unroll
            for (int kx = 0; kx < 3; ++kx) {
                int ix = 2 * x - 1 + kx;
                if ((unsigned)ix >= (unsigned)IN_HW) continue;
                acc += ipc[iy * IN_HW + ix] * wpc[ky * 3 + kx];
            }
        }
    }
    out[idx] = fmaxf(acc, 0.f);
}

__global__ void pool_ef(const float* __restrict__ conv3, const float* __restrict__ ef_w,
                        const float* __restrict__ ef_b, float* __restrict__ keys)
{
    int b = blockIdx.x, tid = threadIdx.x;
    __shared__ float pooled[128];
    if (tid < 128) {
        const float* p = conv3 + (size_t)(b * 128 + tid) * 64;
        float s = 0.f;
        #pragma unroll 8
        for (int i = 0; i < 64; ++i) s += p[i];
        pooled[tid] = s * (1.f / 64.f);
    }
    __syncthreads();
    if (tid < 256) {
        float acc = ef_b[tid];
        const float* wr = ef_w + (size_t)tid * 128;
        for (int c = 0; c < 128; ++c) acc += pooled[c] * wr[c];
        keys[((size_t)b * NK + 240) * H + tid] = acc;
    }
}

// ---------------- persistent fused kernel ----------------
struct KP3 {
    const float *hist;
    const float *e0_Wih,*e0_Whh,*e0_bih,*e0_bhh;
    const float *e1_Wih,*e1_Whh,*e1_bih,*e1_bhh;
    const float *aW_w,*aW_b,*av_w,*av_b;
    const float *d0_Wih,*d0_Whh,*d0_bih,*d0_bhh;
    const float *d1_Wih,*d1_Whh,*d1_bih,*d1_bhh;
    const float *o_w,*o_b;
    float *keys,*h0,*h1,*ctxu,*Sg,*curr,*preds;
    unsigned *bar;
};

__global__ __launch_bounds__(512) void fused3(KP3 P)
{
    extern __shared__ unsigned smem_u[];
    float* fS = (float*)smem_u;
    unsigned* kpL = smem_u + OFF_KP;
    unsigned* ksL = smem_u + OFF_KEYS;
    float* dW    = fS + OFF_DW;     // [0]=d0Wih_ctx [1024]=d0Whh [2048]=d1Wih [3072]=d1Whh (rows: g*256+c for unit j)
    float* sPart = fS + OFF_SPART;
    float* sH2   = fS + OFF_SH2;
    float* sQ    = fS + OFF_SQ;
    float* sExp  = fS + OFF_SEXP;
    float* sAv   = fS + OFF_SAV;
    float* sOw   = fS + OFF_SOW;
    float* sRed  = fS + OFF_SRED;
    float* sE    = fS + OFF_SE;
    float* sWe   = fS;              // encoder weights alias kp region: [0]=e0Whh [1024]=e1Wih [2048]=e1Whh

    const int blk = blockIdx.x, tid = threadIdx.x;
    const int j = blk;                       // owned output unit (all cells)
    const int b = tid & 127, kk = tid >> 7;  // (batch, K-quarter) mapping
    const int r = blk >> 1, hf = blk & 1;    // attention (row, key-half)
    const int kcnt = hf ? (NK - NKH) : NKH;  // 120 : 121
    const int kbase = hf * NKH;

    // ---- stage weights ----
    for (int i = tid; i < 1024; i += 512){
        int g = i >> 8, c = i & 255;
        sWe[i]        = P.e0_Whh[(size_t)(g*H + j)*H + c];
        sWe[1024 + i] = P.e1_Wih[(size_t)(g*H + j)*H + c];
        sWe[2048 + i] = P.e1_Whh[(size_t)(g*H + j)*H + c];
        dW[i]         = P.d0_Wih[(size_t)(g*H + j)*258 + 2 + c];
        dW[1024 + i]  = P.d0_Whh[(size_t)(g*H + j)*H + c];
        dW[2048 + i]  = P.d1_Wih[(size_t)(g*H + j)*H + c];
        dW[3072 + i]  = P.d1_Whh[(size_t)(g*H + j)*H + c];
    }
    if (tid < 256) sAv[tid] = P.av_w[tid];
    if (tid < 512) sOw[tid] = P.o_w[tid];
    if (tid < 4){
        sE[tid]    = P.e0_bih[tid*H + j] + P.e0_bhh[tid*H + j];
        sE[4+tid]  = P.e1_bih[tid*H + j] + P.e1_bhh[tid*H + j];
        sE[8+tid]  = P.d0_bih[tid*H + j] + P.d0_bhh[tid*H + j];
        sE[12+tid] = P.d1_bih[tid*H + j] + P.d1_bhh[tid*H + j];
        sE[16+tid] = P.e0_Wih[(size_t)(tid*H + j)*2 + 0];
        sE[20+tid] = P.e0_Wih[(size_t)(tid*H + j)*2 + 1];
        sE[24+tid] = P.d0_Wih[(size_t)(tid*H + j)*258 + 0];
        sE[28+tid] = P.d0_Wih[(size_t)(tid*H + j)*258 + 1];
    }
    if (tid == 0){ sE[32] = P.av_b[0]; sE[33] = P.o_b[0]; sE[34] = P.o_b[1]; }
    __syncthreads();

    unsigned bstep = 0;
    float creg0 = 0.f, creg1 = 0.f;  // c-states of unit j (tid<128: batch=tid), live whole kernel

    // ================= encoder: 241 phases =================
    for (int p = 0; p <= TE; ++p){
        // --- L0 partials ---
        if (p < TE && p > 0){
            const float4* h4 = (const float4*)(P.h0 + (size_t)(p&1)*BH + b*H + kk*64);
            float a0=0,a1=0,a2=0,a3=0;
            const float4* w0 = (const float4*)(sWe + 0*256 + kk*64);
            const float4* w1 = (const float4*)(sWe + 1*256 + kk*64);
            const float4* w2 = (const float4*)(sWe + 2*256 + kk*64);
            const float4* w3 = (const float4*)(sWe + 3*256 + kk*64);
            #pragma unroll 4
            for (int i = 0; i < 16; ++i){
                float4 hv = h4[i];
                a0 += dot4(hv,w0[i]); a1 += dot4(hv,w1[i]);
                a2 += dot4(hv,w2[i]); a3 += dot4(hv,w3[i]);
            }
            sPart[(0*4+kk)*128+b]=a0; sPart[(1*4+kk)*128+b]=a1;
            sPart[(2*4+kk)*128+b]=a2; sPart[(3*4+kk)*128+b]=a3;
        }
        __syncthreads();
        if (p < TE && tid < 128){
            float x0 = P.hist[((size_t)b*TE + p)*2], x1 = P.hist[((size_t)b*TE + p)*2 + 1];
            float g[4];
            #pragma unroll
            for (int q = 0; q < 4; ++q){
                float gg = sE[q] + x0*sE[16+q] + x1*sE[20+q];
                if (p > 0) gg += sPart[(q*4+0)*128+b] + sPart[(q*4+1)*128+b]
                               + sPart[(q*4+2)*128+b] + sPart[(q*4+3)*128+b];
                g[q] = gg;
            }
            creg0 = sigm(g[1])*creg0 + sigm(g[0])*ftanh(g[2]);
            P.h0[(size_t)((p+1)&1)*BH + b*H + j] = sigm(g[3])*ftanh(creg0);
        }
        __syncthreads();
        // --- L1 partials (step s=p-1; x = enc1 output = h0[p&1]) ---
        if (p >= 1){
            const float4* x4 = (const float4*)(P.h0 + (size_t)(p&1)*BH + b*H + kk*64);
            float a0=0,a1=0,a2=0,a3=0;
            {
                const float4* w0 = (const float4*)(sWe + 1024 + 0*256 + kk*64);
                const float4* w1 = (const float4*)(sWe + 1024 + 1*256 + kk*64);
                const float4* w2 = (const float4*)(sWe + 1024 + 2*256 + kk*64);
                const float4* w3 = (const float4*)(sWe + 1024 + 3*256 + kk*64);
                #pragma unroll 4
                for (int i = 0; i < 16; ++i){
                    float4 xv = x4[i];
                    a0 += dot4(xv,w0[i]); a1 += dot4(xv,w1[i]);
                    a2 += dot4(xv,w2[i]); a3 += dot4(xv,w3[i]);
                }
            }
            if (p > 1){
                const float4* h4 = (const float4*)(P.h1 + (size_t)((p-1)&1)*BH + b*H + kk*64);
                const float4* w0 = (const float4*)(sWe + 2048 + 0*256 + kk*64);
                const float4* w1 = (const float4*)(sWe + 2048 + 1*256 + kk*64);
                const float4* w2 = (const float4*)(sWe + 2048 + 2*256 + kk*64);
                const float4* w3 = (const float4*)(sWe + 2048 + 3*256 + kk*64);
                #pragma unroll 4
                for (int i = 0; i < 16; ++i){
                    float4 hv = h4[i];
                    a0 += dot4(hv,w0[i]); a1 += dot4(hv,w1[i]);
                    a2 += dot4(hv,w2[i]); a3 += dot4(hv,w3[i]);
                }
            }
            sPart[(0*4+kk)*128+b]=a0; sPart[(1*4+kk)*128+b]=a1;
            sPart[(2*4+kk)*128+b]=a2; sPart[(3*4+kk)*128+b]=a3;
        }
        __syncthreads();
        if (p >= 1 && tid < 128){
            int s = p - 1;
            float g[4];
            #pragma unroll
            for (int q = 0; q < 4; ++q)
                g[q] = sE[4+q] + sPart[(q*4+0)*128+b] + sPart[(q*4+1)*128+b]
                               + sPart[(q*4+2)*128+b] + sPart[(q*4+3)*128+b];
            creg1 = sigm(g[1])*creg1 + sigm(g[0])*ftanh(g[2]);
            float hn = sigm(g[3])*ftanh(creg1);
            P.h1[(size_t)(p&1)*BH + b*H + j] = hn;
            P.keys[((size_t)b*NK + s)*H + j] = hn;
        }
        gbar(P.bar, ++bstep);
    }

    // ================= keys_proj into LDS (block-local, bf16) =================
    {
        const int g = tid & 255, kb2 = tid >> 8;  // output unit, key quad select
        for (int kt = 0; kt < 16; ++kt){
            __syncthreads();
            for (int i = tid; i < 2048; i += 512){   // tile: 8 keys x 256 f32
                int kkx = i >> 8, c = i & 255;
                int klx = kt*8 + kkx;
                sPart[i] = (klx < kcnt) ? P.keys[((size_t)r*NK + kbase + klx)*H + c] : 0.f;
            }
            __syncthreads();
            // fill keys_l bf16
            for (int i = tid; i < 1024; i += 512){
                int kkx = i >> 7, dp = i & 127;
                int klx = kt*8 + kkx;
                if (klx < kcnt)
                    ksL[klx*KPSTR + dp] = packbf(sPart[kkx*256 + 2*dp], sPart[kkx*256 + 2*dp + 1]);
            }
            // kp tile: thread (g, kb2) -> keys kb2*4..+3, full 256-dot
            float acc0, acc1, acc2, acc3;
            acc0 = acc1 = acc2 = acc3 = P.aW_b[g];
            {
                const float4* w4 = (const float4*)(P.aW_w + (size_t)g*(2*H) + H);
                const float4* k0 = (const float4*)(sPart + (kb2*4+0)*256);
                const float4* k1 = (const float4*)(sPart + (kb2*4+1)*256);
                const float4* k2 = (const float4*)(sPart + (kb2*4+2)*256);
                const float4* k3 = (const float4*)(sPart + (kb2*4+3)*256);
                #pragma unroll 8
                for (int i = 0; i < 64; ++i){
                    float4 w = w4[i];
                    acc0 += dot4(w,k0[i]); acc1 += dot4(w,k1[i]);
                    acc2 += dot4(w,k2[i]); acc3 += dot4(w,k3[i]);
                }
            }
            float accs[4] = {acc0, acc1, acc2, acc3};
            #pragma unroll
            for (int kkx2 = 0; kkx2 < 4; ++kkx2){
                __syncthreads();
                sH2[kb2*256 + g] = accs[kkx2];   // sH2+sQ = 512-float staging
                __syncthreads();
                if (tid < 256){
                    int kw = tid >> 7, dp = tid & 127;
                    int klx = kt*8 + kw*4 + kkx2;
                    if (klx < kcnt)
                        kpL[klx*KPSTR + dp] = packbf(sH2[kw*256 + 2*dp], sH2[kw*256 + 2*dp + 1]);
                }
            }
        }
    }
    __syncthreads();

    // ================= decoder: 360 steps x 3 stages =================
    float pd1_0=0, pd1_1=0, pd1_2=0, pd1_3=0;
    for (int t = 0; ; ++t){
        // ---- stage A: curr/preds update + attention (row r, key-half hf) ----
        if (tid < 256) sH2[tid] = P.h1[(size_t)(t&1)*BH + (size_t)r*H + tid];
        __syncthreads();
        if (hf == 0 && tid < 64){
            if (t > 0){
                int c = tid >> 5, l = tid & 31;
                float a = 0.f;
                for (int k2 = l; k2 < 256; k2 += 32) a += sH2[k2]*sOw[c*256+k2];
                #pragma unroll
                for (int mk = 16; mk >= 1; mk >>= 1) a += __shfl_xor(a, mk);
                if (l == 0){
                    float cv = P.curr[r*2+c] + sE[33+c] + a;
                    P.curr[r*2+c] = cv;
                    P.preds[((size_t)r*TF + (t-1))*2 + c] = cv;
                }
            } else if (tid < 2){
                P.curr[r*2+tid] = P.hist[((size_t)r*TE + TE-1)*2 + tid];
            }
        }
        if (t == TF) break;
        // q = Wq @ hd2_row
        {
            const int g = tid >> 1, kh2 = tid & 1;
            const float4* w4 = (const float4*)(P.aW_w + (size_t)g*(2*H) + kh2*128);
            const float4* h4 = (const float4*)(sH2 + kh2*128);
            float a = 0.f;
            #pragma unroll 8
            for (int i = 0; i < 32; ++i) a += dot4(w4[i], h4[i]);
            sPart[tid] = a;
        }
        __syncthreads();
        if (tid < 256) sQ[tid] = sPart[2*tid] + sPart[2*tid+1];
        __syncthreads();
        // energies for own keys (2 threads/key, 128 dims each)
        {
            const int kl = tid >> 1, sub = tid & 1;
            float a = 0.f;
            if (kl < kcnt){
                const uint2* kp2 = (const uint2*)(kpL + kl*KPSTR + sub*64);
                const float4* q4 = (const float4*)(sQ + sub*128);
                const float4* a4 = (const float4*)(sAv + sub*128);
                #pragma unroll 8
                for (int i = 0; i < 32; ++i){
                    uint2 v = kp2[i];
                    float4 qv = q4[i], av = a4[i];
                    a += av.x*ftanh(qv.x + blo(v.x)) + av.y*ftanh(qv.y + bhi(v.x))
                       + av.z*ftanh(qv.z + blo(v.y)) + av.w*ftanh(qv.w + bhi(v.y));
                }
            }
            sPart[tid] = a;
        }
        __syncthreads();
        if (tid < 256){
            float ex = 0.f;
            if (tid < kcnt) ex = __expf(sPart[2*tid] + sPart[2*tid+1] + sE[32]);
            sExp[tid] = ex;
            #pragma unroll
            for (int mk = 32; mk >= 1; mk >>= 1) ex += __shfl_xor(ex, mk);
            if ((tid & 63) == 0) sRed[tid >> 6] = ex;
        }
        __syncthreads();
        // unnormalized ctx over own keys (bf16 keys from LDS)
        {
            const int dp = tid & 127, ks = tid >> 7;
            float a0 = 0.f, a1 = 0.f;
            for (int kl = ks; kl < kcnt; kl += 4){
                unsigned v = ksL[kl*KPSTR + dp];
                float e = sExp[kl];
                a0 += e * blo(v); a1 += e * bhi(v);
            }
            sPart[ks*256 + 2*dp] = a0; sPart[ks*256 + 2*dp + 1] = a1;
        }
        __syncthreads();
        if (tid < 128){
            float c0 = sPart[2*tid] + sPart[256+2*tid] + sPart[512+2*tid] + sPart[768+2*tid];
            float c1 = sPart[2*tid+1] + sPart[256+2*tid+1] + sPart[512+2*tid+1] + sPart[768+2*tid+1];
            float2 w2v; w2v.x = c0; w2v.y = c1;
            *(float2*)(P.ctxu + ((size_t)(hf*B + r))*H + 2*tid) = w2v;
        }
        if (tid == 128) P.Sg[hf*B + r] = sRed[0]+sRed[1]+sRed[2]+sRed[3];
        gbar(P.bar, ++bstep);

        // ---- stage B: cell0 (unit j) + d1_Whh partial kept in regs ----
        {
            float invS = 1.f / (P.Sg[b] + P.Sg[B + b]);
            const float4* cu0 = (const float4*)(P.ctxu + (size_t)b*H + kk*64);
            const float4* cu1 = (const float4*)(P.ctxu + (size_t)(B + b)*H + kk*64);
            const float4* h4  = (const float4*)(P.h0 + (size_t)(t&1)*BH + b*H + kk*64);
            const float4* h24 = (const float4*)(P.h1 + (size_t)(t&1)*BH + b*H + kk*64);
            const float4* wc0 = (const float4*)(dW + 0*256 + kk*64);
            const float4* wc1 = (const float4*)(dW + 1*256 + kk*64);
            const float4* wc2 = (const float4*)(dW + 2*256 + kk*64);
            const float4* wc3 = (const float4*)(dW + 3*256 + kk*64);
            const float4* wh0 = (const float4*)(dW + 1024 + 0*256 + kk*64);
            const float4* wh1 = (const float4*)(dW + 1024 + 1*256 + kk*64);
            const float4* wh2 = (const float4*)(dW + 1024 + 2*256 + kk*64);
            const float4* wh3 = (const float4*)(dW + 1024 + 3*256 + kk*64);
            const float4* w10 = (const float4*)(dW + 3072 + 0*256 + kk*64);
            const float4* w11 = (const float4*)(dW + 3072 + 1*256 + kk*64);
            const float4* w12 = (const float4*)(dW + 3072 + 2*256 + kk*64);
            const float4* w13 = (const float4*)(dW + 3072 + 3*256 + kk*64);
            float a0=0,a1=0,a2=0,a3=0;
            pd1_0=0; pd1_1=0; pd1_2=0; pd1_3=0;
            #pragma unroll 4
            for (int i = 0; i < 16; ++i){
                float4 u0 = cu0[i], u1 = cu1[i], hv = h4[i], h2v = h24[i];
                float4 cx;
                cx.x=(u0.x+u1.x)*invS; cx.y=(u0.y+u1.y)*invS;
                cx.z=(u0.z+u1.z)*invS; cx.w=(u0.w+u1.w)*invS;
                a0 += dot4(cx,wc0[i]) + dot4(hv,wh0[i]);
                a1 += dot4(cx,wc1[i]) + dot4(hv,wh1[i]);
                a2 += dot4(cx,wc2[i]) + dot4(hv,wh2[i]);
                a3 += dot4(cx,wc3[i]) + dot4(hv,wh3[i]);
                pd1_0 += dot4(h2v,w10[i]); pd1_1 += dot4(h2v,w11[i]);
                pd1_2 += dot4(h2v,w12[i]); pd1_3 += dot4(h2v,w13[i]);
            }
            sPart[(0*4+kk)*128+b]=a0; sPart[(1*4+kk)*128+b]=a1;
            sPart[(2*4+kk)*128+b]=a2; sPart[(3*4+kk)*128+b]=a3;
        }
        __syncthreads();
        if (tid < 128){
            float u0 = P.curr[tid*2], u1 = P.curr[tid*2+1];
            float g[4];
            #pragma unroll
            for (int q = 0; q < 4; ++q)
                g[q] = sE[8+q] + u0*sE[24+q] + u1*sE[28+q]
                     + sPart[(q*4+0)*128+tid] + sPart[(q*4+1)*128+tid]
                     + sPart[(q*4+2)*128+tid] + sPart[(q*4+3)*128+tid];
            creg0 = sigm(g[1])*creg0 + sigm(g[0])*ftanh(g[2]);
            P.h0[(size_t)((t+1)&1)*BH + (size_t)tid*H + j] = sigm(g[3])*ftanh(creg0);
        }
        gbar(P.bar, ++bstep);

        // ---- stage C: cell1 (unit j): d1_Wih @ hd1_new + stored d1_Whh partial ----
        {
            const float4* h4 = (const float4*)(P.h0 + (size_t)((t+1)&1)*BH + b*H + kk*64);
            const float4* w0 = (const float4*)(dW + 2048 + 0*256 + kk*64);
            const float4* w1 = (const float4*)(dW + 2048 + 1*256 + kk*64);
            const float4* w2 = (const float4*)(dW + 2048 + 2*256 + kk*64);
            const float4* w3 = (const float4*)(dW + 2048 + 3*256 + kk*64);
            float a0=pd1_0, a1=pd1_1, a2=pd1_2, a3=pd1_3;
            #pragma unroll 4
            for (int i = 0; i < 16; ++i){
                float4 hv = h4[i];
                a0 += dot4(hv,w0[i]); a1 += dot4(hv,w1[i]);
                a2 += dot4(hv,w2[i]); a3 += dot4(hv,w3[i]);
            }
            sPart[(0*4+kk)*128+b]=a0; sPart[(1*4+kk)*128+b]=a1;
            sPart[(2*4+kk)*128+b]=a2; sPart[(3*4+kk)*128+b]=a3;
        }
        __syncthreads();
        if (tid < 128){
            float g[4];
            #pragma unroll
            for (int q = 0; q < 4; ++q)
                g[q] = sE[12+q] + sPart[(q*4+0)*128+tid] + sPart[(q*4+1)*128+tid]
                                + sPart[(q*4+2)*128+tid] + sPart[(q*4+3)*128+tid];
            creg1 = sigm(g[1])*creg1 + sigm(g[0])*ftanh(g[2]);
            P.h1[(size_t)((t+1)&1)*BH + (size_t)tid*H + j] = sigm(g[3])*ftanh(creg1);
        }
        gbar(P.bar, ++bstep);
    }
}

extern "C" void kernel_launch(void* const* d_in, const int* in_sizes, int n_in,
                              void* d_out, int out_size, void* d_ws, size_t ws_size,
                              hipStream_t stream)
{
    const float* hist   = (const float*)d_in[0];
    const float* env    = (const float*)d_in[1];
    const float* e0_Wih = (const float*)d_in[2];
    const float* e0_Whh = (const float*)d_in[3];
    const float* e0_bih = (const float*)d_in[4];
    const float* e0_bhh = (const float*)d_in[5];
    const float* e1_Wih = (const float*)d_in[6];
    const float* e1_Whh = (const float*)d_in[7];
    const float* e1_bih = (const float*)d_in[8];
    const float* e1_bhh = (const float*)d_in[9];
    const float* c1w = (const float*)d_in[10];
    const float* c1b = (const float*)d_in[11];
    const float* c2w = (const float*)d_in[12];
    const float* c2b = (const float*)d_in[13];
    const float* c3w = (const float*)d_in[14];
    const float* c3b = (const float*)d_in[15];
    const float* ef_w = (const float*)d_in[16];
    const float* ef_b = (const float*)d_in[17];
    const float* aW_w = (const float*)d_in[18];
    const float* aW_b = (const float*)d_in[19];
    const float* av_w = (const float*)d_in[20];
    const float* av_b = (const float*)d_in[21];
    const float* d0_Wih = (const float*)d_in[22];
    const float* d0_Whh = (const float*)d_in[23];
    const float* d0_bih = (const float*)d_in[24];
    const float* d0_bhh = (const float*)d_in[25];
    const float* d1_Wih = (const float*)d_in[26];
    const float* d1_Whh = (const float*)d_in[27];
    const float* d1_bih = (const float*)d_in[28];
    const float* d1_bhh = (const float*)d_in[29];
    const float* o_w = (const float*)d_in[30];
    const float* o_b = (const float*)d_in[31];

    float* ws = (float*)d_ws;
    size_t off = 0;
    float* keys = ws;            off += (size_t)B*NK*H;     // 7,897,088
    float* convA = ws + off;     // conv scratch: 4,194,304 + 2,097,152 + 1,048,576
    float* convB = convA + 4194304;
    float* convC = convB + 2097152;
    off += 7340032 + 65536;      // conv region (+ slack)
    float* h0   = ws + off; off += 2*BH;
    float* h1   = ws + off; off += 2*BH;
    float* ctxu = ws + off; off += 2*BH;      // [2][128][256] unnormalized ctx halves
    float* Sg   = ws + off; off += 256;       // [2][128] softmax denominators
    float* curr = ws + off; off += 256;
    unsigned* bar = (unsigned*)(ws + off);    // 512 uints

    hipMemsetAsync(bar, 0, 512*sizeof(unsigned), stream);

    // ---- CNN branch (one-shot) ----
    conv_relu<18, 32, 64, 32><<<(B*32*32*32)/256, 256, 0, stream>>>(env, c1w, c1b, convA);
    conv_relu<32, 64, 32, 16><<<(B*64*16*16)/256, 256, 0, stream>>>(convA, c2w, c2b, convB);
    conv_relu<64, 128, 16, 8><<<(B*128*8*8)/256, 256, 0, stream>>>(convB, c3w, c3b, convC);
    pool_ef<<<B, 256, 0, stream>>>(convC, ef_w, ef_b, keys);

    // ---- persistent cooperative kernel ----
    hipFuncSetAttribute((const void*)fused3, hipFuncAttributeMaxDynamicSharedMemorySize, SMEM_BYTES);
    KP3 Pk = {
        hist,
        e0_Wih, e0_Whh, e0_bih, e0_bhh,
        e1_Wih, e1_Whh, e1_bih, e1_bhh,
        aW_w, aW_b, av_w, av_b,
        d0_Wih, d0_Whh, d0_bih, d0_bhh,
        d1_Wih, d1_Whh, d1_bih, d1_bhh,
        o_w, o_b,
        keys, h0, h1, ctxu, Sg, curr, (float*)d_out,
        bar
    };
    void* args[] = { &Pk };
    hipLaunchCooperativeKernel((void*)fused3, dim3(256), dim3(512), args, SMEM_BYTES, stream);
}